// Round 9
// baseline (224.120 us; speedup 1.0000x reference)
//
#include <hip/hip_runtime.h>
#include <hip/hip_bf16.h>
#include <hip/hip_fp16.h>
#include <math.h>

#define N_NODES 10000
#define N_EDGES 320000
#define IN_SIZE 256
#define H1 8
#define D1 64
#define F1 512
#define H2 1
#define D2 64
#define F2 64

using f16x8 = __attribute__((ext_vector_type(8))) _Float16;
using f32x4 = __attribute__((ext_vector_type(4))) float;

// ---- conversions ----
__global__ void f32_to_f16_vec(const float* __restrict__ in, __half* __restrict__ out, int n4) {
  int i = blockIdx.x * blockDim.x + threadIdx.x;
  if (i < n4) {
    float4 v = reinterpret_cast<const float4*>(in)[i];
    reinterpret_cast<__half2*>(out)[i * 2 + 0] = __floats2half2_rn(v.x, v.y);
    reinterpret_cast<__half2*>(out)[i * 2 + 1] = __floats2half2_rn(v.z, v.w);
  }
}

// W [K][N] f32 -> WT [N][K] f16
__global__ void transpose_to_f16(const float* __restrict__ in, __half* __restrict__ out,
                                 int K, int N) {
  int i = blockIdx.x * blockDim.x + threadIdx.x;
  if (i < K * N) {
    int k = i / N, n = i % N;
    out[(size_t)n * K + k] = __float2half(in[i]);
  }
}

// ---- MFMA f16 GEMM (64x64 tile / block, 4 waves, no LDS) + el/er epilogue ----
template <int KSTEPS>
__global__ __launch_bounds__(256) void gemm_mfma(
    const __half* __restrict__ A, const __half* __restrict__ BT,
    __half* __restrict__ Ch, const float* __restrict__ al,
    const float* __restrict__ ar, float* __restrict__ el,
    float* __restrict__ er, int M, int Ncols, int H) {
  constexpr int K = KSTEPS * 32;
  int tid = threadIdx.x;
  int w = tid >> 6, lane = tid & 63;
  int rowBase = blockIdx.y * 64 + w * 16;
  int colBase = blockIdx.x * 64;
  int r16 = lane & 15;
  int ko = lane >> 4;
  int arow = rowBase + r16;
  if (arow >= M) arow = M - 1;
  const f16x8* Ap = reinterpret_cast<const f16x8*>(A + (size_t)arow * K + ko * 8);
  const __half* Bbase = BT + (size_t)colBase * K + ko * 8;
  f32x4 acc[4] = {};
#pragma unroll
  for (int kk = 0; kk < KSTEPS; ++kk) {
    f16x8 af = Ap[kk * 4];
#pragma unroll
    for (int c = 0; c < 4; ++c) {
      f16x8 bf = *reinterpret_cast<const f16x8*>(
          Bbase + (size_t)(c * 16 + r16) * K + kk * 32);
      acc[c] = __builtin_amdgcn_mfma_f32_16x16x32_f16(af, bf, acc[c], 0, 0, 0);
    }
  }
  int h = colBase >> 6;
  float alv[4], arv[4];
#pragma unroll
  for (int c = 0; c < 4; ++c) {
    alv[c] = al[colBase + c * 16 + r16];
    arv[c] = ar[colBase + c * 16 + r16];
  }
#pragma unroll
  for (int r = 0; r < 4; ++r) {
    int row = rowBase + (lane >> 4) * 4 + r;
    bool ok = row < M;
    float pl = 0.f, pr = 0.f;
#pragma unroll
    for (int c = 0; c < 4; ++c) {
      float v = acc[c][r];
      if (ok) Ch[(size_t)row * Ncols + colBase + c * 16 + r16] = __float2half(v);
      pl += v * alv[c];
      pr += v * arv[c];
    }
#pragma unroll
    for (int o = 8; o > 0; o >>= 1) {
      pl += __shfl_xor(pl, o);
      pr += __shfl_xor(pr, o);
    }
    if (r16 == 0 && ok) {
      el[(size_t)row * H + h] = pl;
      er[(size_t)row * H + h] = pr;
    }
  }
}

// ---- CSR build ----
__global__ void hist_kernel(const int* __restrict__ dst, int* __restrict__ counts, int E) {
  int e = blockIdx.x * blockDim.x + threadIdx.x;
  if (e < E) atomicAdd(&counts[dst[e]], 1);
}

__global__ __launch_bounds__(1024) void scan_kernel(const int* __restrict__ counts,
                                                    int* __restrict__ row_off,
                                                    int* __restrict__ cursor, int N) {
  __shared__ int part[1024];
  int tid = threadIdx.x;
  int T = blockDim.x;
  int chunk = (N + T - 1) / T;
  int beg = tid * chunk;
  int end = min(beg + chunk, N);
  int s = 0;
  for (int i = beg; i < end; ++i) s += counts[i];
  part[tid] = s;
  __syncthreads();
  for (int off = 1; off < T; off <<= 1) {
    int v = (tid >= off) ? part[tid - off] : 0;
    __syncthreads();
    part[tid] += v;
    __syncthreads();
  }
  int run = (tid > 0) ? part[tid - 1] : 0;
  for (int i = beg; i < end; ++i) {
    row_off[i] = run;
    cursor[i] = run;
    run += counts[i];
  }
  if (tid == T - 1) row_off[N] = run;
}

__global__ void scatter_kernel(const int* __restrict__ src, const int* __restrict__ dst,
                               int* __restrict__ cursor, int* __restrict__ src_csr,
                               int* __restrict__ dst_csr, int E) {
  int e = blockIdx.x * blockDim.x + threadIdx.x;
  if (e < E) {
    int d = dst[e];
    int p = atomicAdd(&cursor[d], 1);
    src_csr[p] = src[e];
    dst_csr[p] = d;
  }
}

// ---- degree counting sort (descending) ----
__global__ void dhist_kernel(const int* __restrict__ counts, int* __restrict__ dhist, int N) {
  int n = blockIdx.x * blockDim.x + threadIdx.x;
  if (n < N) atomicAdd(&dhist[min(counts[n], 128)], 1);
}
__global__ void dscan_kernel(const int* __restrict__ dhist, int* __restrict__ dcur) {
  if (threadIdx.x == 0) {
    int run = 0;
    for (int d = 128; d >= 0; --d) { dcur[d] = run; run += dhist[d]; }
  }
}
__global__ void dorder_kernel(const int* __restrict__ counts, int* __restrict__ dcur,
                              int* __restrict__ nord, int N) {
  int n = blockIdx.x * blockDim.x + threadIdx.x;
  if (n < N) {
    int d = min(counts[n], 128);
    nord[atomicAdd(&dcur[d], 1)] = n;
  }
}

// ---- CSR-ordered leaky logits (removes double-indirect gather from gat loop) ----
__global__ void logits1_kernel(const int* __restrict__ src_csr, const int* __restrict__ dst_csr,
                               const float* __restrict__ el, const float* __restrict__ er,
                               float* __restrict__ lg, int n8) {
  int t = blockIdx.x * blockDim.x + threadIdx.x;
  if (t < n8) {
    int p = t >> 3, h = t & 7;
    float v = el[src_csr[p] * 8 + h] + er[dst_csr[p] * 8 + h];
    lg[t] = (v >= 0.f) ? v : 0.2f * v;
  }
}
__global__ void logits2_kernel(const int* __restrict__ src_csr, const int* __restrict__ dst_csr,
                               const float* __restrict__ el, const float* __restrict__ er,
                               float* __restrict__ lg, int E) {
  int p = blockIdx.x * blockDim.x + threadIdx.x;
  if (p < E) {
    float v = el[src_csr[p]] + er[dst_csr[p]];
    lg[p] = (v >= 0.f) ? v : 0.2f * v;
  }
}

__device__ __forceinline__ int bcast_i(int v, int l) {
  return __builtin_amdgcn_readlane(v, l);
}

// ---- fused GAT layer 1: one wave per node, 16-edge chunks, prefetched ----
// logit phase: lane = e*8+h (e = edge slot 0..7, two logits per lane);
// agg phase: lane = (head=lane&7, quad=lane>>3), ch = head*64 + quad*8.
template <int NPB>
__global__ __launch_bounds__(NPB * 64) void gat_l1_kernel(
    const int* __restrict__ row_off, const int* __restrict__ src_csr,
    const float* __restrict__ lgb, const __half* __restrict__ fth,
    const float* __restrict__ bias, __half* __restrict__ out,
    const int* __restrict__ nord) {
  int t = threadIdx.x;
  int w = t >> 6, lane = t & 63;
  int n = nord[blockIdx.x * NPB + w];
  int e = lane >> 3;
  int hl = lane & 7;
  int ch = hl * 64 + e * 8;
  int bp = hl * 4;
  int beg = row_off[n], end = row_off[n + 1];
  float m_run = -INFINITY, s_run = 0.f;
  float acc[8] = {0.f, 0.f, 0.f, 0.f, 0.f, 0.f, 0.f, 0.f};
  if (beg < end) {
    int ia = min(beg + e, end - 1);
    int ib = min(beg + 8 + e, end - 1);
    int sa = src_csr[ia], sb = src_csr[ib];
    float la = lgb[ia * 8 + hl], lb = lgb[ib * 8 + hl];
    for (int c = beg; c < end; c += 16) {
      int cs_a = sa, cs_b = sb;
      float lg_a = (c + e < end) ? la : -INFINITY;
      float lg_b = (c + 8 + e < end) ? lb : -INFINITY;
      int cn = c + 16;
      if (cn < end) {  // prefetch next chunk (hides under softmax+gather)
        ia = min(cn + e, end - 1);
        ib = min(cn + 8 + e, end - 1);
        sa = src_csr[ia]; sb = src_csr[ib];
        la = lgb[ia * 8 + hl]; lb = lgb[ib * 8 + hl];
      }
      float m_c = fmaxf(lg_a, lg_b);
      m_c = fmaxf(m_c, __shfl_xor(m_c, 8));
      m_c = fmaxf(m_c, __shfl_xor(m_c, 16));
      m_c = fmaxf(m_c, __shfl_xor(m_c, 32));
      float m_new = fmaxf(m_run, m_c);
      float ex_a = __expf(lg_a - m_new);
      float ex_b = __expf(lg_b - m_new);
      float sum_c = ex_a + ex_b;
      sum_c += __shfl_xor(sum_c, 8);
      sum_c += __shfl_xor(sum_c, 16);
      sum_c += __shfl_xor(sum_c, 32);
      float scale = __expf(m_run - m_new);  // first chunk: exp(-inf)=0
#pragma unroll
      for (int i = 0; i < 8; ++i) acc[i] *= scale;
      s_run = s_run * scale + sum_c;
      m_run = m_new;
      int cnt = end - c;
      int exa = __float_as_int(ex_a), exb = __float_as_int(ex_b);
#pragma unroll
      for (int hb = 0; hb < 2; ++hb) {
        int base = hb * 8;
        int csx = hb ? cs_b : cs_a;
        int exx = hb ? exb : exa;
        uint4 fv[8];
#pragma unroll
        for (int j = 0; j < 8; ++j) {
          if (base + j < cnt) {
            int s0 = bcast_i(csx, j * 8);
            fv[j] = *reinterpret_cast<const uint4*>(fth + (size_t)s0 * F1 + ch);
          }
        }
#pragma unroll
        for (int j = 0; j < 8; ++j) {
          if (base + j < cnt) {
            float ee = __int_as_float(
                __builtin_amdgcn_ds_bpermute(bp + j * 32, exx));
            float2 f0 = __half22float2(*reinterpret_cast<const __half2*>(&fv[j].x));
            float2 f1 = __half22float2(*reinterpret_cast<const __half2*>(&fv[j].y));
            float2 f2 = __half22float2(*reinterpret_cast<const __half2*>(&fv[j].z));
            float2 f3 = __half22float2(*reinterpret_cast<const __half2*>(&fv[j].w));
            acc[0] += ee * f0.x; acc[1] += ee * f0.y;
            acc[2] += ee * f1.x; acc[3] += ee * f1.y;
            acc[4] += ee * f2.x; acc[5] += ee * f2.y;
            acc[6] += ee * f3.x; acc[7] += ee * f3.y;
          }
        }
      }
    }
  }
  float inv = (s_run > 0.f) ? (1.f / s_run) : 0.f;
  uint4 pack;
  __half2* ph = reinterpret_cast<__half2*>(&pack);
#pragma unroll
  for (int i = 0; i < 4; ++i) {
    float v0 = acc[2 * i + 0] * inv + bias[ch + 2 * i + 0];
    float v1 = acc[2 * i + 1] * inv + bias[ch + 2 * i + 1];
    v0 = (v0 > 0.f) ? v0 : (__expf(v0) - 1.f);  // ELU
    v1 = (v1 > 0.f) ? v1 : (__expf(v1) - 1.f);
    ph[i] = __floats2half2_rn(v0, v1);
  }
  *reinterpret_cast<uint4*>(out + (size_t)n * F1 + ch) = pack;
}

// ---- fused GAT layer 2 (H=1, D=64): one wave per node, 64-edge chunks ----
// logit phase: lane = edge slot (full-wave softmax); agg phase: rounds of 8
// edges, lane = (edge sub-slot r8 = lane>>3, channel quad q = lane&7).
template <int NPB>
__global__ __launch_bounds__(NPB * 64) void gat_l2_kernel(
    const int* __restrict__ row_off, const int* __restrict__ src_csr,
    const float* __restrict__ lgb, const __half* __restrict__ fth,
    const float* __restrict__ bias, float* __restrict__ out,
    const int* __restrict__ nord) {
  int t = threadIdx.x;
  int w = t >> 6, lane = t & 63;
  int n = nord[blockIdx.x * NPB + w];
  int q = lane & 7;
  int r8 = lane >> 3;
  int beg = row_off[n], end = row_off[n + 1];
  float m_run = -INFINITY, s_run = 0.f;
  float acc[8] = {0.f, 0.f, 0.f, 0.f, 0.f, 0.f, 0.f, 0.f};
  if (beg < end) {
    int ia = min(beg + lane, end - 1);
    int sa = src_csr[ia];
    float la = lgb[ia];
    for (int c = beg; c < end; c += 64) {
      int cs = sa;
      float lg = (c + lane < end) ? la : -INFINITY;
      int cn = c + 64;
      if (cn < end) {
        ia = min(cn + lane, end - 1);
        sa = src_csr[ia];
        la = lgb[ia];
      }
      float m_c = lg;
#pragma unroll
      for (int o = 32; o > 0; o >>= 1) m_c = fmaxf(m_c, __shfl_xor(m_c, o));
      float m_new = fmaxf(m_run, m_c);
      float ex = __expf(lg - m_new);
      float sum_c = ex;
#pragma unroll
      for (int o = 32; o > 0; o >>= 1) sum_c += __shfl_xor(sum_c, o);
      float scale = __expf(m_run - m_new);
#pragma unroll
      for (int i = 0; i < 8; ++i) acc[i] *= scale;
      s_run = s_run * scale + sum_c;
      m_run = m_new;
      int cnt = end - c; if (cnt > 64) cnt = 64;
      int exb = __float_as_int(ex);
#pragma unroll
      for (int r = 0; r < 8; ++r) {
        if (r * 8 < cnt) {
          int eidx = r * 8 + r8;
          float ee = __int_as_float(__builtin_amdgcn_ds_bpermute(eidx * 4, exb));
          int s0 = __builtin_amdgcn_ds_bpermute(eidx * 4, cs);
          if (eidx < cnt) {
            uint4 fv = *reinterpret_cast<const uint4*>(fth + (size_t)s0 * F2 + q * 8);
            float2 f0 = __half22float2(*reinterpret_cast<const __half2*>(&fv.x));
            float2 f1 = __half22float2(*reinterpret_cast<const __half2*>(&fv.y));
            float2 f2 = __half22float2(*reinterpret_cast<const __half2*>(&fv.z));
            float2 f3 = __half22float2(*reinterpret_cast<const __half2*>(&fv.w));
            acc[0] += ee * f0.x; acc[1] += ee * f0.y;
            acc[2] += ee * f1.x; acc[3] += ee * f1.y;
            acc[4] += ee * f2.x; acc[5] += ee * f2.y;
            acc[6] += ee * f3.x; acc[7] += ee * f3.y;
          }
        }
      }
    }
  }
#pragma unroll
  for (int i = 0; i < 8; ++i) {
    acc[i] += __shfl_xor(acc[i], 8);
    acc[i] += __shfl_xor(acc[i], 16);
    acc[i] += __shfl_xor(acc[i], 32);
  }
  float inv = (s_run > 0.f) ? (1.f / s_run) : 0.f;
  if (r8 == 0) {
    float o[8];
#pragma unroll
    for (int i = 0; i < 8; ++i) o[i] = acc[i] * inv + bias[q * 8 + i];
    float* op = &out[(size_t)n * F2 + q * 8];
    *reinterpret_cast<float4*>(op) = make_float4(o[0], o[1], o[2], o[3]);
    *reinterpret_cast<float4*>(op + 4) = make_float4(o[4], o[5], o[6], o[7]);
  }
}

extern "C" void kernel_launch(void* const* d_in, const int* in_sizes, int n_in,
                              void* d_out, int out_size, void* d_ws, size_t ws_size,
                              hipStream_t stream) {
  const float* x   = (const float*)d_in[0];
  const int*   src = (const int*)d_in[1];
  const int*   dst = (const int*)d_in[2];
  const float* W1  = (const float*)d_in[3];
  const float* al1 = (const float*)d_in[4];
  const float* ar1 = (const float*)d_in[5];
  const float* b1  = (const float*)d_in[6];
  const float* W2  = (const float*)d_in[7];
  const float* al2 = (const float*)d_in[8];
  const float* ar2 = (const float*)d_in[9];
  const float* b2  = (const float*)d_in[10];
  float* out = (float*)d_out;

  char* ws = (char*)d_ws;
  size_t off = 0;
  auto alloc = [&](size_t bytes) -> void* {
    void* p = ws + off;
    off += (bytes + 255) & ~(size_t)255;
    return p;
  };
  size_t zbeg = off;
  int* counts = (int*)alloc((size_t)N_NODES * 4);
  int* dhist  = (int*)alloc(129 * 4);
  size_t zend = off;
  int* dcur   = (int*)alloc(129 * 4);
  int* nord   = (int*)alloc((size_t)N_NODES * 4);
  __half* xh   = (__half*)alloc((size_t)N_NODES * IN_SIZE * 2);
  __half* W1T  = (__half*)alloc((size_t)IN_SIZE * F1 * 2);
  __half* W2T  = (__half*)alloc((size_t)F1 * F2 * 2);
  __half* ft1h = (__half*)alloc((size_t)N_NODES * F1 * 2);
  __half* h1h  = (__half*)alloc((size_t)N_NODES * F1 * 2);
  __half* ft2h = (__half*)alloc((size_t)N_NODES * F2 * 2);
  float* el1 = (float*)alloc((size_t)N_NODES * H1 * 4);
  float* er1 = (float*)alloc((size_t)N_NODES * H1 * 4);
  float* el2 = (float*)alloc((size_t)N_NODES * 4);
  float* er2 = (float*)alloc((size_t)N_NODES * 4);
  float* lgb1 = (float*)alloc((size_t)N_EDGES * H1 * 4);
  float* lgb2 = (float*)alloc((size_t)N_EDGES * 4);
  int* row_off = (int*)alloc((size_t)(N_NODES + 1) * 4);
  int* cursor  = (int*)alloc((size_t)N_NODES * 4);
  int* src_csr = (int*)alloc((size_t)N_EDGES * 4);
  int* dst_csr = (int*)alloc((size_t)N_EDGES * 4);
  (void)ws_size; (void)in_sizes; (void)n_in; (void)out_size;

  hipMemsetAsync(ws + zbeg, 0, zend - zbeg, stream);

  dim3 b256(256);
  int egrid = (N_EDGES + 255) / 256;
  int ngrid = (N_NODES + 255) / 256;

  // CSR build + degree sort
  hist_kernel<<<egrid, b256, 0, stream>>>(dst, counts, N_EDGES);
  scan_kernel<<<1, 1024, 0, stream>>>(counts, row_off, cursor, N_NODES);
  scatter_kernel<<<egrid, b256, 0, stream>>>(src, dst, cursor, src_csr, dst_csr, N_EDGES);
  dhist_kernel<<<ngrid, b256, 0, stream>>>(counts, dhist, N_NODES);
  dscan_kernel<<<1, 64, 0, stream>>>(dhist, dcur);
  dorder_kernel<<<ngrid, b256, 0, stream>>>(counts, dcur, nord, N_NODES);

  // input conversions
  f32_to_f16_vec<<<(N_NODES * IN_SIZE / 4 + 255) / 256, b256, 0, stream>>>(
      x, xh, N_NODES * IN_SIZE / 4);
  transpose_to_f16<<<(IN_SIZE * F1 + 255) / 256, b256, 0, stream>>>(W1, W1T, IN_SIZE, F1);
  transpose_to_f16<<<(F1 * F2 + 255) / 256, b256, 0, stream>>>(W2, W2T, F1, F2);

  // ---- layer 1 ----
  gemm_mfma<IN_SIZE / 32><<<dim3(F1 / 64, (N_NODES + 63) / 64), b256, 0, stream>>>(
      xh, W1T, ft1h, al1, ar1, el1, er1, N_NODES, F1, H1);
  logits1_kernel<<<(N_EDGES * 8 + 255) / 256, b256, 0, stream>>>(
      src_csr, dst_csr, el1, er1, lgb1, N_EDGES * 8);
  gat_l1_kernel<4><<<N_NODES / 4, 256, 0, stream>>>(
      row_off, src_csr, lgb1, ft1h, b1, h1h, nord);

  // ---- layer 2 ----
  gemm_mfma<F1 / 32><<<dim3(F2 / 64, (N_NODES + 63) / 64), b256, 0, stream>>>(
      h1h, W2T, ft2h, al2, ar2, el2, er2, N_NODES, F2, H2);
  logits2_kernel<<<egrid, b256, 0, stream>>>(src_csr, dst_csr, el2, er2, lgb2, N_EDGES);
  gat_l2_kernel<4><<<N_NODES / 4, 256, 0, stream>>>(
      row_off, src_csr, lgb2, ft2h, b2, out, nord);
}

// Round 10
// 176.062 us; speedup vs baseline: 1.2730x; 1.2730x over previous
//
#include <hip/hip_runtime.h>
#include <hip/hip_bf16.h>
#include <hip/hip_fp16.h>
#include <math.h>

#define N_NODES 10000
#define N_EDGES 320000
#define IN_SIZE 256
#define H1 8
#define D1 64
#define F1 512
#define H2 1
#define D2 64
#define F2 64

using f16x8 = __attribute__((ext_vector_type(8))) _Float16;
using f32x4 = __attribute__((ext_vector_type(4))) float;

// ---- fused prep: x->f16, W1^T->f16, W2^T->f16, dst histogram ----
#define PREP_X (N_NODES * IN_SIZE / 4)
#define PREP_W1 (IN_SIZE * F1)
#define PREP_W2 (F1 * F2)
__global__ void prep_kernel(const float* __restrict__ x, __half* __restrict__ xh,
                            const float* __restrict__ W1, __half* __restrict__ W1T,
                            const float* __restrict__ W2, __half* __restrict__ W2T,
                            const int* __restrict__ dst, int* __restrict__ counts) {
  int i = blockIdx.x * blockDim.x + threadIdx.x;
  if (i < PREP_X) {
    float4 v = reinterpret_cast<const float4*>(x)[i];
    reinterpret_cast<__half2*>(xh)[i * 2 + 0] = __floats2half2_rn(v.x, v.y);
    reinterpret_cast<__half2*>(xh)[i * 2 + 1] = __floats2half2_rn(v.z, v.w);
    return;
  }
  i -= PREP_X;
  if (i < PREP_W1) {
    int k = i / F1, n = i % F1;
    W1T[(size_t)n * IN_SIZE + k] = __float2half(W1[i]);
    return;
  }
  i -= PREP_W1;
  if (i < PREP_W2) {
    int k = i / F2, n = i % F2;
    W2T[(size_t)n * F1 + k] = __float2half(W2[i]);
    return;
  }
  i -= PREP_W2;
  if (i < N_EDGES) atomicAdd(&counts[dst[i]], 1);
}

// ---- scan + row_off/cursor + degree counting-sort (desc, unstable) ----
__global__ __launch_bounds__(1024) void scan_kernel(const int* __restrict__ counts,
                                                    int* __restrict__ row_off,
                                                    int* __restrict__ cursor,
                                                    int* __restrict__ nord, int N) {
  __shared__ int part[1024];
  __shared__ int bins[129];
  __shared__ int bcur[129];
  int tid = threadIdx.x;
  int T = blockDim.x;
  int chunk = (N + T - 1) / T;
  int beg = tid * chunk;
  int end = min(beg + chunk, N);
  int s = 0;
  for (int i = beg; i < end; ++i) s += counts[i];
  part[tid] = s;
  if (tid < 129) bins[tid] = 0;
  __syncthreads();
  for (int off = 1; off < T; off <<= 1) {
    int v = (tid >= off) ? part[tid - off] : 0;
    __syncthreads();
    part[tid] += v;
    __syncthreads();
  }
  int run = (tid > 0) ? part[tid - 1] : 0;
  for (int i = beg; i < end; ++i) {
    row_off[i] = run;
    cursor[i] = run;
    run += counts[i];
    atomicAdd(&bins[min(counts[i], 128)], 1);
  }
  if (tid == T - 1) row_off[N] = run;
  __syncthreads();
  if (tid == 0) {
    int r = 0;
    for (int d = 128; d >= 0; --d) { bcur[d] = r; r += bins[d]; }
  }
  __syncthreads();
  for (int i = beg; i < end; ++i) {
    int d = min(counts[i], 128);
    nord[atomicAdd(&bcur[d], 1)] = i;
  }
}

__global__ void scatter_kernel(const int* __restrict__ src, const int* __restrict__ dst,
                               int* __restrict__ cursor, int* __restrict__ src_csr,
                               int* __restrict__ dst_csr, int E) {
  int e = blockIdx.x * blockDim.x + threadIdx.x;
  if (e < E) {
    int d = dst[e];
    int p = atomicAdd(&cursor[d], 1);
    src_csr[p] = src[e];
    dst_csr[p] = d;
  }
}

// ---- MFMA f16 GEMM (64x64 tile / block, 4 waves, no LDS) + el/er epilogue ----
template <int KSTEPS>
__global__ __launch_bounds__(256) void gemm_mfma(
    const __half* __restrict__ A, const __half* __restrict__ BT,
    __half* __restrict__ Ch, const float* __restrict__ al,
    const float* __restrict__ ar, float* __restrict__ el,
    float* __restrict__ er, int M, int Ncols, int H) {
  constexpr int K = KSTEPS * 32;
  int tid = threadIdx.x;
  int w = tid >> 6, lane = tid & 63;
  int rowBase = blockIdx.y * 64 + w * 16;
  int colBase = blockIdx.x * 64;
  int r16 = lane & 15;
  int ko = lane >> 4;
  int arow = rowBase + r16;
  if (arow >= M) arow = M - 1;
  const f16x8* Ap = reinterpret_cast<const f16x8*>(A + (size_t)arow * K + ko * 8);
  const __half* Bbase = BT + (size_t)colBase * K + ko * 8;
  f32x4 acc[4] = {};
#pragma unroll
  for (int kk = 0; kk < KSTEPS; ++kk) {
    f16x8 af = Ap[kk * 4];
#pragma unroll
    for (int c = 0; c < 4; ++c) {
      f16x8 bf = *reinterpret_cast<const f16x8*>(
          Bbase + (size_t)(c * 16 + r16) * K + kk * 32);
      acc[c] = __builtin_amdgcn_mfma_f32_16x16x32_f16(af, bf, acc[c], 0, 0, 0);
    }
  }
  int h = colBase >> 6;
  float alv[4], arv[4];
#pragma unroll
  for (int c = 0; c < 4; ++c) {
    alv[c] = al[colBase + c * 16 + r16];
    arv[c] = ar[colBase + c * 16 + r16];
  }
#pragma unroll
  for (int r = 0; r < 4; ++r) {
    int row = rowBase + (lane >> 4) * 4 + r;
    bool ok = row < M;
    float pl = 0.f, pr = 0.f;
#pragma unroll
    for (int c = 0; c < 4; ++c) {
      float v = acc[c][r];
      if (ok) Ch[(size_t)row * Ncols + colBase + c * 16 + r16] = __float2half(v);
      pl += v * alv[c];
      pr += v * arv[c];
    }
#pragma unroll
    for (int o = 8; o > 0; o >>= 1) {
      pl += __shfl_xor(pl, o);
      pr += __shfl_xor(pr, o);
    }
    if (r16 == 0 && ok) {
      el[(size_t)row * H + h] = pl;
      er[(size_t)row * H + h] = pr;
    }
  }
}

// ---- CSR-ordered un-normalized attention weights: ex = exp(leaky(el+er)) ----
// No max subtraction (logit magnitudes are small; clamp guards overflow).
// Denominator is accumulated for free inside the aggregation kernels.
__global__ void exp1_kernel(const int* __restrict__ src_csr, const int* __restrict__ dst_csr,
                            const float* __restrict__ el, const float* __restrict__ er,
                            float* __restrict__ ex, int n8) {
  int t = blockIdx.x * blockDim.x + threadIdx.x;
  if (t < n8) {
    int p = t >> 3, h = t & 7;
    float v = el[src_csr[p] * 8 + h] + er[dst_csr[p] * 8 + h];
    v = (v >= 0.f) ? v : 0.2f * v;
    ex[t] = __expf(fminf(v, 80.f));
  }
}
__global__ void exp2_kernel(const int* __restrict__ src_csr, const int* __restrict__ dst_csr,
                            const float* __restrict__ el, const float* __restrict__ er,
                            float* __restrict__ ex, int E) {
  int p = blockIdx.x * blockDim.x + threadIdx.x;
  if (p < E) {
    float v = el[src_csr[p]] + er[dst_csr[p]];
    v = (v >= 0.f) ? v : 0.2f * v;
    ex[p] = __expf(fminf(v, 80.f));
  }
}

// ---- aggregation layer 1: pure SpMM, block = node, wave = 128-ch tile ----
// lane = (edge slot e = lane>>4, 16-lane slice: ch = tile*128 + (lane&15)*8).
// Each lane loads ITS OWN edge's 16B ft slice + its ex. No cross-lane ops in
// the loop; denominator accumulated alongside; final reduce over 4 edge slots.
__global__ __launch_bounds__(256) void agg1_kernel(
    const int* __restrict__ row_off, const int* __restrict__ src_csr,
    const float* __restrict__ ex_csr, const __half* __restrict__ fth,
    const float* __restrict__ bias, __half* __restrict__ out,
    const int* __restrict__ nord) {
  int t = threadIdx.x;
  int w = t >> 6, lane = t & 63;
  int n = nord[blockIdx.x];
  int e = lane >> 4;
  int sub = lane & 15;
  int chb = w * 128 + sub * 8;
  int h = (chb >> 6);
  int beg = row_off[n], end = row_off[n + 1];
  float s_run = 0.f;
  float acc[8] = {0.f, 0.f, 0.f, 0.f, 0.f, 0.f, 0.f, 0.f};
  if (beg < end) {
    int i0 = min(beg + e, end - 1);
    int sP = src_csr[i0];
    float exP = (beg + e < end) ? ex_csr[i0 * 8 + h] : 0.f;
    for (int c = beg; c < end; c += 4) {
      int sC = sP;
      float exC = exP;
      int cn = c + 4;
      if (cn < end) {
        int i2 = min(cn + e, end - 1);
        sP = src_csr[i2];
        exP = (cn + e < end) ? ex_csr[i2 * 8 + h] : 0.f;
      }
      uint4 fv = *reinterpret_cast<const uint4*>(fth + (size_t)sC * F1 + chb);
      float2 f0 = __half22float2(*reinterpret_cast<const __half2*>(&fv.x));
      float2 f1 = __half22float2(*reinterpret_cast<const __half2*>(&fv.y));
      float2 f2 = __half22float2(*reinterpret_cast<const __half2*>(&fv.z));
      float2 f3 = __half22float2(*reinterpret_cast<const __half2*>(&fv.w));
      acc[0] += exC * f0.x; acc[1] += exC * f0.y;
      acc[2] += exC * f1.x; acc[3] += exC * f1.y;
      acc[4] += exC * f2.x; acc[5] += exC * f2.y;
      acc[6] += exC * f3.x; acc[7] += exC * f3.y;
      s_run += exC;
    }
  }
  // reduce over 4 edge slots (xor 16, 32)
#pragma unroll
  for (int i = 0; i < 8; ++i) {
    acc[i] += __shfl_xor(acc[i], 16);
    acc[i] += __shfl_xor(acc[i], 32);
  }
  s_run += __shfl_xor(s_run, 16);
  s_run += __shfl_xor(s_run, 32);
  if (e == 0) {
    float inv = (s_run > 0.f) ? (1.f / s_run) : 0.f;
    uint4 pack;
    __half2* ph = reinterpret_cast<__half2*>(&pack);
#pragma unroll
    for (int i = 0; i < 4; ++i) {
      float v0 = acc[2 * i + 0] * inv + bias[chb + 2 * i + 0];
      float v1 = acc[2 * i + 1] * inv + bias[chb + 2 * i + 1];
      v0 = (v0 > 0.f) ? v0 : (__expf(v0) - 1.f);  // ELU
      v1 = (v1 > 0.f) ? v1 : (__expf(v1) - 1.f);
      ph[i] = __floats2half2_rn(v0, v1);
    }
    *reinterpret_cast<uint4*>(out + (size_t)n * F1 + chb) = pack;
  }
}

// ---- aggregation layer 2 (H=1, D=64): wave per node ----
// lane = (edge slot e = lane>>3, ch quad q = lane&7); own-edge 16B loads.
template <int NPB>
__global__ __launch_bounds__(NPB * 64) void agg2_kernel(
    const int* __restrict__ row_off, const int* __restrict__ src_csr,
    const float* __restrict__ ex_csr, const __half* __restrict__ fth,
    const float* __restrict__ bias, float* __restrict__ out,
    const int* __restrict__ nord) {
  int t = threadIdx.x;
  int w = t >> 6, lane = t & 63;
  int n = nord[blockIdx.x * NPB + w];
  int e = lane >> 3;
  int q = lane & 7;
  int chb = q * 8;
  int beg = row_off[n], end = row_off[n + 1];
  float s_run = 0.f;
  float acc[8] = {0.f, 0.f, 0.f, 0.f, 0.f, 0.f, 0.f, 0.f};
  if (beg < end) {
    int i0 = min(beg + e, end - 1);
    int sP = src_csr[i0];
    float exP = (beg + e < end) ? ex_csr[i0] : 0.f;
    for (int c = beg; c < end; c += 8) {
      int sC = sP;
      float exC = exP;
      int cn = c + 8;
      if (cn < end) {
        int i2 = min(cn + e, end - 1);
        sP = src_csr[i2];
        exP = (cn + e < end) ? ex_csr[i2] : 0.f;
      }
      uint4 fv = *reinterpret_cast<const uint4*>(fth + (size_t)sC * F2 + chb);
      float2 f0 = __half22float2(*reinterpret_cast<const __half2*>(&fv.x));
      float2 f1 = __half22float2(*reinterpret_cast<const __half2*>(&fv.y));
      float2 f2 = __half22float2(*reinterpret_cast<const __half2*>(&fv.z));
      float2 f3 = __half22float2(*reinterpret_cast<const __half2*>(&fv.w));
      acc[0] += exC * f0.x; acc[1] += exC * f0.y;
      acc[2] += exC * f1.x; acc[3] += exC * f1.y;
      acc[4] += exC * f2.x; acc[5] += exC * f2.y;
      acc[6] += exC * f3.x; acc[7] += exC * f3.y;
      s_run += exC;
    }
  }
  // reduce over 8 edge slots (xor 8, 16, 32)
#pragma unroll
  for (int i = 0; i < 8; ++i) {
    acc[i] += __shfl_xor(acc[i], 8);
    acc[i] += __shfl_xor(acc[i], 16);
    acc[i] += __shfl_xor(acc[i], 32);
  }
  s_run += __shfl_xor(s_run, 8);
  s_run += __shfl_xor(s_run, 16);
  s_run += __shfl_xor(s_run, 32);
  if (e == 0) {
    float inv = (s_run > 0.f) ? (1.f / s_run) : 0.f;
    float o[8];
#pragma unroll
    for (int i = 0; i < 8; ++i) o[i] = acc[i] * inv + bias[chb + i];
    float* op = &out[(size_t)n * F2 + chb];
    *reinterpret_cast<float4*>(op) = make_float4(o[0], o[1], o[2], o[3]);
    *reinterpret_cast<float4*>(op + 4) = make_float4(o[4], o[5], o[6], o[7]);
  }
}

extern "C" void kernel_launch(void* const* d_in, const int* in_sizes, int n_in,
                              void* d_out, int out_size, void* d_ws, size_t ws_size,
                              hipStream_t stream) {
  const float* x   = (const float*)d_in[0];
  const int*   src = (const int*)d_in[1];
  const int*   dst = (const int*)d_in[2];
  const float* W1  = (const float*)d_in[3];
  const float* al1 = (const float*)d_in[4];
  const float* ar1 = (const float*)d_in[5];
  const float* b1  = (const float*)d_in[6];
  const float* W2  = (const float*)d_in[7];
  const float* al2 = (const float*)d_in[8];
  const float* ar2 = (const float*)d_in[9];
  const float* b2  = (const float*)d_in[10];
  float* out = (float*)d_out;

  char* ws = (char*)d_ws;
  size_t off = 0;
  auto alloc = [&](size_t bytes) -> void* {
    void* p = ws + off;
    off += (bytes + 255) & ~(size_t)255;
    return p;
  };
  size_t zbeg = off;
  int* counts = (int*)alloc((size_t)N_NODES * 4);
  size_t zend = off;
  int* nord   = (int*)alloc((size_t)N_NODES * 4);
  __half* xh   = (__half*)alloc((size_t)N_NODES * IN_SIZE * 2);
  __half* W1T  = (__half*)alloc((size_t)IN_SIZE * F1 * 2);
  __half* W2T  = (__half*)alloc((size_t)F1 * F2 * 2);
  __half* ft1h = (__half*)alloc((size_t)N_NODES * F1 * 2);
  __half* h1h  = (__half*)alloc((size_t)N_NODES * F1 * 2);
  __half* ft2h = (__half*)alloc((size_t)N_NODES * F2 * 2);
  float* el1 = (float*)alloc((size_t)N_NODES * H1 * 4);
  float* er1 = (float*)alloc((size_t)N_NODES * H1 * 4);
  float* el2 = (float*)alloc((size_t)N_NODES * 4);
  float* er2 = (float*)alloc((size_t)N_NODES * 4);
  float* ex1 = (float*)alloc((size_t)N_EDGES * H1 * 4);
  float* ex2 = (float*)alloc((size_t)N_EDGES * 4);
  int* row_off = (int*)alloc((size_t)(N_NODES + 1) * 4);
  int* cursor  = (int*)alloc((size_t)N_NODES * 4);
  int* src_csr = (int*)alloc((size_t)N_EDGES * 4);
  int* dst_csr = (int*)alloc((size_t)N_EDGES * 4);
  (void)ws_size; (void)in_sizes; (void)n_in; (void)out_size;

  hipMemsetAsync(ws + zbeg, 0, zend - zbeg, stream);

  dim3 b256(256);
  int egrid = (N_EDGES + 255) / 256;
  int prep_total = PREP_X + PREP_W1 + PREP_W2 + N_EDGES;

  // prep (x cvt + W transposes + dst histogram) then CSR
  prep_kernel<<<(prep_total + 255) / 256, b256, 0, stream>>>(
      x, xh, W1, W1T, W2, W2T, dst, counts);
  scan_kernel<<<1, 1024, 0, stream>>>(counts, row_off, cursor, nord, N_NODES);
  scatter_kernel<<<egrid, b256, 0, stream>>>(src, dst, cursor, src_csr, dst_csr, N_EDGES);

  // ---- layer 1 ----
  gemm_mfma<IN_SIZE / 32><<<dim3(F1 / 64, (N_NODES + 63) / 64), b256, 0, stream>>>(
      xh, W1T, ft1h, al1, ar1, el1, er1, N_NODES, F1, H1);
  exp1_kernel<<<(N_EDGES * 8 + 255) / 256, b256, 0, stream>>>(
      src_csr, dst_csr, el1, er1, ex1, N_EDGES * 8);
  agg1_kernel<<<N_NODES, b256, 0, stream>>>(
      row_off, src_csr, ex1, ft1h, b1, h1h, nord);

  // ---- layer 2 ----
  gemm_mfma<F1 / 32><<<dim3(F2 / 64, (N_NODES + 63) / 64), b256, 0, stream>>>(
      h1h, W2T, ft2h, al2, ar2, el2, er2, N_NODES, F2, H2);
  exp2_kernel<<<egrid, b256, 0, stream>>>(src_csr, dst_csr, el2, er2, ex2, N_EDGES);
  agg2_kernel<4><<<N_NODES / 4, b256, 0, stream>>>(
      row_off, src_csr, ex2, ft2h, b2, out, nord);
}

// Round 11
// 162.900 us; speedup vs baseline: 1.3758x; 1.0808x over previous
//
#include <hip/hip_runtime.h>
#include <hip/hip_bf16.h>
#include <hip/hip_fp16.h>
#include <math.h>

#define N_NODES 10000
#define N_EDGES 320000
#define IN_SIZE 256
#define H1 8
#define D1 64
#define F1 512
#define H2 1
#define D2 64
#define F2 64

using f16x8 = __attribute__((ext_vector_type(8))) _Float16;
using f32x4 = __attribute__((ext_vector_type(4))) float;

// ---- fused prep: x->f16, W1^T->f16, W2^T->f16, dst histogram ----
#define PREP_X (N_NODES * IN_SIZE / 4)
#define PREP_W1 (IN_SIZE * F1)
#define PREP_W2 (F1 * F2)
__global__ void prep_kernel(const float* __restrict__ x, __half* __restrict__ xh,
                            const float* __restrict__ W1, __half* __restrict__ W1T,
                            const float* __restrict__ W2, __half* __restrict__ W2T,
                            const int* __restrict__ dst, int* __restrict__ counts) {
  int i = blockIdx.x * blockDim.x + threadIdx.x;
  if (i < PREP_X) {
    float4 v = reinterpret_cast<const float4*>(x)[i];
    reinterpret_cast<__half2*>(xh)[i * 2 + 0] = __floats2half2_rn(v.x, v.y);
    reinterpret_cast<__half2*>(xh)[i * 2 + 1] = __floats2half2_rn(v.z, v.w);
    return;
  }
  i -= PREP_X;
  if (i < PREP_W1) {
    int k = i / F1, n = i % F1;
    W1T[(size_t)n * IN_SIZE + k] = __float2half(W1[i]);
    return;
  }
  i -= PREP_W1;
  if (i < PREP_W2) {
    int k = i / F2, n = i % F2;
    W2T[(size_t)n * F1 + k] = __float2half(W2[i]);
    return;
  }
  i -= PREP_W2;
  if (i < N_EDGES) atomicAdd(&counts[dst[i]], 1);
}

// ---- scan + row_off/cursor + degree counting-sort (desc, unstable) ----
__global__ __launch_bounds__(1024) void scan_kernel(const int* __restrict__ counts,
                                                    int* __restrict__ row_off,
                                                    int* __restrict__ cursor,
                                                    int* __restrict__ nord, int N) {
  __shared__ int part[1024];
  __shared__ int bins[129];
  __shared__ int bcur[129];
  int tid = threadIdx.x;
  int T = blockDim.x;
  int chunk = (N + T - 1) / T;
  int beg = tid * chunk;
  int end = min(beg + chunk, N);
  int s = 0;
  for (int i = beg; i < end; ++i) s += counts[i];
  part[tid] = s;
  if (tid < 129) bins[tid] = 0;
  __syncthreads();
  for (int off = 1; off < T; off <<= 1) {
    int v = (tid >= off) ? part[tid - off] : 0;
    __syncthreads();
    part[tid] += v;
    __syncthreads();
  }
  int run = (tid > 0) ? part[tid - 1] : 0;
  for (int i = beg; i < end; ++i) {
    row_off[i] = run;
    cursor[i] = run;
    run += counts[i];
    atomicAdd(&bins[min(counts[i], 128)], 1);
  }
  if (tid == T - 1) row_off[N] = run;
  __syncthreads();
  if (tid == 0) {
    int r = 0;
    for (int d = 128; d >= 0; --d) { bcur[d] = r; r += bins[d]; }
  }
  __syncthreads();
  for (int i = beg; i < end; ++i) {
    int d = min(counts[i], 128);
    nord[atomicAdd(&bcur[d], 1)] = i;
  }
}

__global__ void scatter_kernel(const int* __restrict__ src, const int* __restrict__ dst,
                               int* __restrict__ cursor, int* __restrict__ src_csr, int E) {
  int e = blockIdx.x * blockDim.x + threadIdx.x;
  if (e < E) {
    int p = atomicAdd(&cursor[dst[e]], 1);
    src_csr[p] = src[e];
  }
}

// ---- MFMA f16 GEMM (64x64 tile / block, 4 waves, no LDS) + el/er epilogue ----
template <int KSTEPS>
__global__ __launch_bounds__(256) void gemm_mfma(
    const __half* __restrict__ A, const __half* __restrict__ BT,
    __half* __restrict__ Ch, const float* __restrict__ al,
    const float* __restrict__ ar, float* __restrict__ el,
    float* __restrict__ er, int M, int Ncols, int H) {
  constexpr int K = KSTEPS * 32;
  int tid = threadIdx.x;
  int w = tid >> 6, lane = tid & 63;
  int rowBase = blockIdx.y * 64 + w * 16;
  int colBase = blockIdx.x * 64;
  int r16 = lane & 15;
  int ko = lane >> 4;
  int arow = rowBase + r16;
  if (arow >= M) arow = M - 1;
  const f16x8* Ap = reinterpret_cast<const f16x8*>(A + (size_t)arow * K + ko * 8);
  const __half* Bbase = BT + (size_t)colBase * K + ko * 8;
  f32x4 acc[4] = {};
#pragma unroll
  for (int kk = 0; kk < KSTEPS; ++kk) {
    f16x8 af = Ap[kk * 4];
#pragma unroll
    for (int c = 0; c < 4; ++c) {
      f16x8 bf = *reinterpret_cast<const f16x8*>(
          Bbase + (size_t)(c * 16 + r16) * K + kk * 32);
      acc[c] = __builtin_amdgcn_mfma_f32_16x16x32_f16(af, bf, acc[c], 0, 0, 0);
    }
  }
  int h = colBase >> 6;
  float alv[4], arv[4];
#pragma unroll
  for (int c = 0; c < 4; ++c) {
    alv[c] = al[colBase + c * 16 + r16];
    arv[c] = ar[colBase + c * 16 + r16];
  }
#pragma unroll
  for (int r = 0; r < 4; ++r) {
    int row = rowBase + (lane >> 4) * 4 + r;
    bool ok = row < M;
    float pl = 0.f, pr = 0.f;
#pragma unroll
    for (int c = 0; c < 4; ++c) {
      float v = acc[c][r];
      if (ok) Ch[(size_t)row * Ncols + colBase + c * 16 + r16] = __float2half(v);
      pl += v * alv[c];
      pr += v * arv[c];
    }
#pragma unroll
    for (int o = 8; o > 0; o >>= 1) {
      pl += __shfl_xor(pl, o);
      pr += __shfl_xor(pr, o);
    }
    if (r16 == 0 && ok) {
      el[(size_t)row * H + h] = pl;
      er[(size_t)row * H + h] = pr;
    }
  }
}

__device__ __forceinline__ float leaky_exp(float v) {
  v = (v >= 0.f) ? v : 0.2f * v;
  return __expf(fminf(v, 80.f));
}

// ---- aggregation layer 1 (exp fused): block = node, wave = 128-ch tile ----
// lane = (edge slot e = lane>>4, slice sub = lane&15); ch = w*128 + sub*8;
// head h = ch>>6. 3-stage pipeline: src 2 chunks ahead, el/ft 1 chunk ahead.
// Un-normalized weights ex = exp(leaky(el+er)); denominator accumulated
// in-loop; reduce over 4 edge slots at the end.
__global__ __launch_bounds__(256) void agg1_kernel(
    const int* __restrict__ row_off, const int* __restrict__ src_csr,
    const float* __restrict__ el, const float* __restrict__ er,
    const __half* __restrict__ fth, const float* __restrict__ bias,
    __half* __restrict__ out, const int* __restrict__ nord) {
  int t = threadIdx.x;
  int w = t >> 6, lane = t & 63;
  int n = nord[blockIdx.x];
  int e = lane >> 4;
  int sub = lane & 15;
  int chb = w * 128 + sub * 8;
  int h = chb >> 6;
  int beg = row_off[n], end = row_off[n + 1];
  float er_h = er[n * 8 + h];
  float s_run = 0.f;
  float acc[8] = {0.f, 0.f, 0.f, 0.f, 0.f, 0.f, 0.f, 0.f};
  if (beg < end) {
    int iA = min(beg + e, end - 1);
    bool okA = (beg + e) < end;
    int sA = src_csr[iA];
    int iB = min(beg + 4 + e, end - 1);
    bool okB = (beg + 4 + e) < end;
    int sB = src_csr[iB];
    float elA = el[sA * 8 + h];
    uint4 ftA = *reinterpret_cast<const uint4*>(fth + (size_t)sA * F1 + chb);
    for (int c = beg; c < end; c += 4) {
      // prefetch: src 2 ahead, el/ft 1 ahead
      int iC = min(c + 8 + e, end - 1);
      bool okC = (c + 8 + e) < end;
      int sC = src_csr[iC];
      float elB = el[sB * 8 + h];
      uint4 ftB = *reinterpret_cast<const uint4*>(fth + (size_t)sB * F1 + chb);
      // compute current
      float ex = okA ? leaky_exp(elA + er_h) : 0.f;
      float2 f0 = __half22float2(*reinterpret_cast<const __half2*>(&ftA.x));
      float2 f1 = __half22float2(*reinterpret_cast<const __half2*>(&ftA.y));
      float2 f2 = __half22float2(*reinterpret_cast<const __half2*>(&ftA.z));
      float2 f3 = __half22float2(*reinterpret_cast<const __half2*>(&ftA.w));
      acc[0] += ex * f0.x; acc[1] += ex * f0.y;
      acc[2] += ex * f1.x; acc[3] += ex * f1.y;
      acc[4] += ex * f2.x; acc[5] += ex * f2.y;
      acc[6] += ex * f3.x; acc[7] += ex * f3.y;
      s_run += ex;
      // shift pipeline
      sA = sB; okA = okB; elA = elB; ftA = ftB;
      sB = sC; okB = okC;
    }
  }
  // reduce over 4 edge slots (xor 16, 32)
#pragma unroll
  for (int i = 0; i < 8; ++i) {
    acc[i] += __shfl_xor(acc[i], 16);
    acc[i] += __shfl_xor(acc[i], 32);
  }
  s_run += __shfl_xor(s_run, 16);
  s_run += __shfl_xor(s_run, 32);
  if (e == 0) {
    float inv = (s_run > 0.f) ? (1.f / s_run) : 0.f;
    uint4 pack;
    __half2* ph = reinterpret_cast<__half2*>(&pack);
#pragma unroll
    for (int i = 0; i < 4; ++i) {
      float v0 = acc[2 * i + 0] * inv + bias[chb + 2 * i + 0];
      float v1 = acc[2 * i + 1] * inv + bias[chb + 2 * i + 1];
      v0 = (v0 > 0.f) ? v0 : (__expf(v0) - 1.f);  // ELU
      v1 = (v1 > 0.f) ? v1 : (__expf(v1) - 1.f);
      ph[i] = __floats2half2_rn(v0, v1);
    }
    *reinterpret_cast<uint4*>(out + (size_t)n * F1 + chb) = pack;
  }
}

// ---- aggregation layer 2 (H=1, exp fused): wave per node ----
// lane = (edge slot e = lane>>3, ch quad q = lane&7); same 3-stage pipeline.
template <int NPB>
__global__ __launch_bounds__(NPB * 64) void agg2_kernel(
    const int* __restrict__ row_off, const int* __restrict__ src_csr,
    const float* __restrict__ el, const float* __restrict__ er,
    const __half* __restrict__ fth, const float* __restrict__ bias,
    float* __restrict__ out, const int* __restrict__ nord) {
  int t = threadIdx.x;
  int w = t >> 6, lane = t & 63;
  int n = nord[blockIdx.x * NPB + w];
  int e = lane >> 3;
  int q = lane & 7;
  int chb = q * 8;
  int beg = row_off[n], end = row_off[n + 1];
  float er_n = er[n];
  float s_run = 0.f;
  float acc[8] = {0.f, 0.f, 0.f, 0.f, 0.f, 0.f, 0.f, 0.f};
  if (beg < end) {
    int iA = min(beg + e, end - 1);
    bool okA = (beg + e) < end;
    int sA = src_csr[iA];
    int iB = min(beg + 8 + e, end - 1);
    bool okB = (beg + 8 + e) < end;
    int sB = src_csr[iB];
    float elA = el[sA];
    uint4 ftA = *reinterpret_cast<const uint4*>(fth + (size_t)sA * F2 + chb);
    for (int c = beg; c < end; c += 8) {
      int iC = min(c + 16 + e, end - 1);
      bool okC = (c + 16 + e) < end;
      int sC = src_csr[iC];
      float elB = el[sB];
      uint4 ftB = *reinterpret_cast<const uint4*>(fth + (size_t)sB * F2 + chb);
      float ex = okA ? leaky_exp(elA + er_n) : 0.f;
      float2 f0 = __half22float2(*reinterpret_cast<const __half2*>(&ftA.x));
      float2 f1 = __half22float2(*reinterpret_cast<const __half2*>(&ftA.y));
      float2 f2 = __half22float2(*reinterpret_cast<const __half2*>(&ftA.z));
      float2 f3 = __half22float2(*reinterpret_cast<const __half2*>(&ftA.w));
      acc[0] += ex * f0.x; acc[1] += ex * f0.y;
      acc[2] += ex * f1.x; acc[3] += ex * f1.y;
      acc[4] += ex * f2.x; acc[5] += ex * f2.y;
      acc[6] += ex * f3.x; acc[7] += ex * f3.y;
      s_run += ex;
      sA = sB; okA = okB; elA = elB; ftA = ftB;
      sB = sC; okB = okC;
    }
  }
  // reduce over 8 edge slots (xor 8, 16, 32)
#pragma unroll
  for (int i = 0; i < 8; ++i) {
    acc[i] += __shfl_xor(acc[i], 8);
    acc[i] += __shfl_xor(acc[i], 16);
    acc[i] += __shfl_xor(acc[i], 32);
  }
  s_run += __shfl_xor(s_run, 8);
  s_run += __shfl_xor(s_run, 16);
  s_run += __shfl_xor(s_run, 32);
  if (e == 0) {
    float inv = (s_run > 0.f) ? (1.f / s_run) : 0.f;
    float o[8];
#pragma unroll
    for (int i = 0; i < 8; ++i) o[i] = acc[i] * inv + bias[chb + i];
    float* op = &out[(size_t)n * F2 + chb];
    *reinterpret_cast<float4*>(op) = make_float4(o[0], o[1], o[2], o[3]);
    *reinterpret_cast<float4*>(op + 4) = make_float4(o[4], o[5], o[6], o[7]);
  }
}

extern "C" void kernel_launch(void* const* d_in, const int* in_sizes, int n_in,
                              void* d_out, int out_size, void* d_ws, size_t ws_size,
                              hipStream_t stream) {
  const float* x   = (const float*)d_in[0];
  const int*   src = (const int*)d_in[1];
  const int*   dst = (const int*)d_in[2];
  const float* W1  = (const float*)d_in[3];
  const float* al1 = (const float*)d_in[4];
  const float* ar1 = (const float*)d_in[5];
  const float* b1  = (const float*)d_in[6];
  const float* W2  = (const float*)d_in[7];
  const float* al2 = (const float*)d_in[8];
  const float* ar2 = (const float*)d_in[9];
  const float* b2  = (const float*)d_in[10];
  float* out = (float*)d_out;

  char* ws = (char*)d_ws;
  size_t off = 0;
  auto alloc = [&](size_t bytes) -> void* {
    void* p = ws + off;
    off += (bytes + 255) & ~(size_t)255;
    return p;
  };
  size_t zbeg = off;
  int* counts = (int*)alloc((size_t)N_NODES * 4);
  size_t zend = off;
  int* nord   = (int*)alloc((size_t)N_NODES * 4);
  __half* xh   = (__half*)alloc((size_t)N_NODES * IN_SIZE * 2);
  __half* W1T  = (__half*)alloc((size_t)IN_SIZE * F1 * 2);
  __half* W2T  = (__half*)alloc((size_t)F1 * F2 * 2);
  __half* ft1h = (__half*)alloc((size_t)N_NODES * F1 * 2);
  __half* h1h  = (__half*)alloc((size_t)N_NODES * F1 * 2);
  __half* ft2h = (__half*)alloc((size_t)N_NODES * F2 * 2);
  float* el1 = (float*)alloc((size_t)N_NODES * H1 * 4);
  float* er1 = (float*)alloc((size_t)N_NODES * H1 * 4);
  float* el2 = (float*)alloc((size_t)N_NODES * 4);
  float* er2 = (float*)alloc((size_t)N_NODES * 4);
  int* row_off = (int*)alloc((size_t)(N_NODES + 1) * 4);
  int* cursor  = (int*)alloc((size_t)N_NODES * 4);
  int* src_csr = (int*)alloc((size_t)N_EDGES * 4);
  (void)ws_size; (void)in_sizes; (void)n_in; (void)out_size;

  hipMemsetAsync(ws + zbeg, 0, zend - zbeg, stream);

  dim3 b256(256);
  int egrid = (N_EDGES + 255) / 256;
  int prep_total = PREP_X + PREP_W1 + PREP_W2 + N_EDGES;

  // prep (x cvt + W transposes + dst histogram) then CSR (+degree sort)
  prep_kernel<<<(prep_total + 255) / 256, b256, 0, stream>>>(
      x, xh, W1, W1T, W2, W2T, dst, counts);
  scan_kernel<<<1, 1024, 0, stream>>>(counts, row_off, cursor, nord, N_NODES);
  scatter_kernel<<<egrid, b256, 0, stream>>>(src, dst, cursor, src_csr, N_EDGES);

  // ---- layer 1 ----
  gemm_mfma<IN_SIZE / 32><<<dim3(F1 / 64, (N_NODES + 63) / 64), b256, 0, stream>>>(
      xh, W1T, ft1h, al1, ar1, el1, er1, N_NODES, F1, H1);
  agg1_kernel<<<N_NODES, b256, 0, stream>>>(
      row_off, src_csr, el1, er1, ft1h, b1, h1h, nord);

  // ---- layer 2 ----
  gemm_mfma<F1 / 32><<<dim3(F2 / 64, (N_NODES + 63) / 64), b256, 0, stream>>>(
      h1h, W2T, ft2h, al2, ar2, el2, er2, N_NODES, F2, H2);
  agg2_kernel<4><<<N_NODES / 4, b256, 0, stream>>>(
      row_off, src_csr, el2, er2, ft2h, b2, out, nord);
}

// Round 12
// 154.929 us; speedup vs baseline: 1.4466x; 1.0514x over previous
//
#include <hip/hip_runtime.h>
#include <hip/hip_bf16.h>
#include <hip/hip_fp16.h>
#include <math.h>

#define N_NODES 10000
#define N_EDGES 320000
#define IN_SIZE 256
#define H1 8
#define D1 64
#define F1 512
#define H2 1
#define D2 64
#define F2 64

using f16x8 = __attribute__((ext_vector_type(8))) _Float16;
using f32x4 = __attribute__((ext_vector_type(4))) float;

// ---- fused prep: x->f16, W1^T->f16, W2^T->f16, dst histogram ----
#define PREP_X (N_NODES * IN_SIZE / 4)
#define PREP_W1 (IN_SIZE * F1)
#define PREP_W2 (F1 * F2)
__global__ void prep_kernel(const float* __restrict__ x, __half* __restrict__ xh,
                            const float* __restrict__ W1, __half* __restrict__ W1T,
                            const float* __restrict__ W2, __half* __restrict__ W2T,
                            const int* __restrict__ dst, int* __restrict__ counts) {
  int i = blockIdx.x * blockDim.x + threadIdx.x;
  if (i < PREP_X) {
    float4 v = reinterpret_cast<const float4*>(x)[i];
    reinterpret_cast<__half2*>(xh)[i * 2 + 0] = __floats2half2_rn(v.x, v.y);
    reinterpret_cast<__half2*>(xh)[i * 2 + 1] = __floats2half2_rn(v.z, v.w);
    return;
  }
  i -= PREP_X;
  if (i < PREP_W1) {
    int k = i / F1, n = i % F1;
    W1T[(size_t)n * IN_SIZE + k] = __float2half(W1[i]);
    return;
  }
  i -= PREP_W1;
  if (i < PREP_W2) {
    int k = i / F2, n = i % F2;
    W2T[(size_t)n * F1 + k] = __float2half(W2[i]);
    return;
  }
  i -= PREP_W2;
  if (i < N_EDGES) atomicAdd(&counts[dst[i]], 1);
}

// ---- scan + row_off/cursor + degree counting-sort (desc, unstable) ----
__global__ __launch_bounds__(1024) void scan_kernel(const int* __restrict__ counts,
                                                    int* __restrict__ row_off,
                                                    int* __restrict__ cursor,
                                                    int* __restrict__ nord, int N) {
  __shared__ int part[1024];
  __shared__ int bins[129];
  __shared__ int bcur[129];
  int tid = threadIdx.x;
  int T = blockDim.x;
  int chunk = (N + T - 1) / T;
  int beg = tid * chunk;
  int end = min(beg + chunk, N);
  int s = 0;
  for (int i = beg; i < end; ++i) s += counts[i];
  part[tid] = s;
  if (tid < 129) bins[tid] = 0;
  __syncthreads();
  for (int off = 1; off < T; off <<= 1) {
    int v = (tid >= off) ? part[tid - off] : 0;
    __syncthreads();
    part[tid] += v;
    __syncthreads();
  }
  int run = (tid > 0) ? part[tid - 1] : 0;
  for (int i = beg; i < end; ++i) {
    row_off[i] = run;
    cursor[i] = run;
    run += counts[i];
    atomicAdd(&bins[min(counts[i], 128)], 1);
  }
  if (tid == T - 1) row_off[N] = run;
  __syncthreads();
  if (tid == 0) {
    int r = 0;
    for (int d = 128; d >= 0; --d) { bcur[d] = r; r += bins[d]; }
  }
  __syncthreads();
  for (int i = beg; i < end; ++i) {
    int d = min(counts[i], 128);
    nord[atomicAdd(&bcur[d], 1)] = i;
  }
}

// ---- merged dispatch: GEMM1 (MFMA) blocks + scatter blocks ----
// Blocks [0, GEMM1_BLOCKS): 64x64 MFMA tiles of ft1 = xh @ W1T^T (+f16 C,
// el/er epilogue). Blocks [GEMM1_BLOCKS, +SCAT_BLOCKS): CSR scatter.
// The two are independent (gemm needs prep, scatter needs scan); merging
// overlaps the latency/atomic-bound scatter under the MFMA-bound gemm.
#define GEMM1_RB ((N_NODES + 63) / 64)
#define GEMM1_BLOCKS (8 * GEMM1_RB)
#define SCAT_BLOCKS ((N_EDGES + 255) / 256)
__global__ __launch_bounds__(256) void gemm1_scatter_kernel(
    const __half* __restrict__ A, const __half* __restrict__ BT,
    __half* __restrict__ Ch, const float* __restrict__ al,
    const float* __restrict__ ar, float* __restrict__ el,
    float* __restrict__ er,
    const int* __restrict__ src, const int* __restrict__ dst,
    int* __restrict__ cursor, int* __restrict__ src_csr) {
  int tid = threadIdx.x;
  if (blockIdx.x >= GEMM1_BLOCKS) {
    int e = (blockIdx.x - GEMM1_BLOCKS) * 256 + tid;
    if (e < N_EDGES) {
      int p = atomicAdd(&cursor[dst[e]], 1);
      src_csr[p] = src[e];
    }
    return;
  }
  constexpr int K = IN_SIZE;
  constexpr int KSTEPS = IN_SIZE / 32;
  int w = tid >> 6, lane = tid & 63;
  int rowBase = (blockIdx.x >> 3) * 64 + w * 16;
  int colBase = (blockIdx.x & 7) * 64;
  int r16 = lane & 15;
  int ko = lane >> 4;
  int arow = rowBase + r16;
  if (arow >= N_NODES) arow = N_NODES - 1;
  const f16x8* Ap = reinterpret_cast<const f16x8*>(A + (size_t)arow * K + ko * 8);
  const __half* Bbase = BT + (size_t)colBase * K + ko * 8;
  f32x4 acc[4] = {};
#pragma unroll
  for (int kk = 0; kk < KSTEPS; ++kk) {
    f16x8 af = Ap[kk * 4];
#pragma unroll
    for (int c = 0; c < 4; ++c) {
      f16x8 bf = *reinterpret_cast<const f16x8*>(
          Bbase + (size_t)(c * 16 + r16) * K + kk * 32);
      acc[c] = __builtin_amdgcn_mfma_f32_16x16x32_f16(af, bf, acc[c], 0, 0, 0);
    }
  }
  int h = colBase >> 6;
  float alv[4], arv[4];
#pragma unroll
  for (int c = 0; c < 4; ++c) {
    alv[c] = al[colBase + c * 16 + r16];
    arv[c] = ar[colBase + c * 16 + r16];
  }
#pragma unroll
  for (int r = 0; r < 4; ++r) {
    int row = rowBase + (lane >> 4) * 4 + r;
    bool ok = row < N_NODES;
    float pl = 0.f, pr = 0.f;
#pragma unroll
    for (int c = 0; c < 4; ++c) {
      float v = acc[c][r];
      if (ok) Ch[(size_t)row * F1 + colBase + c * 16 + r16] = __float2half(v);
      pl += v * alv[c];
      pr += v * arv[c];
    }
#pragma unroll
    for (int o = 8; o > 0; o >>= 1) {
      pl += __shfl_xor(pl, o);
      pr += __shfl_xor(pr, o);
    }
    if (r16 == 0 && ok) {
      el[(size_t)row * H1 + h] = pl;
      er[(size_t)row * H1 + h] = pr;
    }
  }
}

// ---- MFMA f16 GEMM (64x64 tile / block, 4 waves, no LDS) + el/er epilogue ----
template <int KSTEPS>
__global__ __launch_bounds__(256) void gemm_mfma(
    const __half* __restrict__ A, const __half* __restrict__ BT,
    __half* __restrict__ Ch, const float* __restrict__ al,
    const float* __restrict__ ar, float* __restrict__ el,
    float* __restrict__ er, int M, int Ncols, int H) {
  constexpr int K = KSTEPS * 32;
  int tid = threadIdx.x;
  int w = tid >> 6, lane = tid & 63;
  int rowBase = blockIdx.y * 64 + w * 16;
  int colBase = blockIdx.x * 64;
  int r16 = lane & 15;
  int ko = lane >> 4;
  int arow = rowBase + r16;
  if (arow >= M) arow = M - 1;
  const f16x8* Ap = reinterpret_cast<const f16x8*>(A + (size_t)arow * K + ko * 8);
  const __half* Bbase = BT + (size_t)colBase * K + ko * 8;
  f32x4 acc[4] = {};
#pragma unroll
  for (int kk = 0; kk < KSTEPS; ++kk) {
    f16x8 af = Ap[kk * 4];
#pragma unroll
    for (int c = 0; c < 4; ++c) {
      f16x8 bf = *reinterpret_cast<const f16x8*>(
          Bbase + (size_t)(c * 16 + r16) * K + kk * 32);
      acc[c] = __builtin_amdgcn_mfma_f32_16x16x32_f16(af, bf, acc[c], 0, 0, 0);
    }
  }
  int h = colBase >> 6;
  float alv[4], arv[4];
#pragma unroll
  for (int c = 0; c < 4; ++c) {
    alv[c] = al[colBase + c * 16 + r16];
    arv[c] = ar[colBase + c * 16 + r16];
  }
#pragma unroll
  for (int r = 0; r < 4; ++r) {
    int row = rowBase + (lane >> 4) * 4 + r;
    bool ok = row < M;
    float pl = 0.f, pr = 0.f;
#pragma unroll
    for (int c = 0; c < 4; ++c) {
      float v = acc[c][r];
      if (ok) Ch[(size_t)row * Ncols + colBase + c * 16 + r16] = __float2half(v);
      pl += v * alv[c];
      pr += v * arv[c];
    }
#pragma unroll
    for (int o = 8; o > 0; o >>= 1) {
      pl += __shfl_xor(pl, o);
      pr += __shfl_xor(pr, o);
    }
    if (r16 == 0 && ok) {
      el[(size_t)row * H + h] = pl;
      er[(size_t)row * H + h] = pr;
    }
  }
}

__device__ __forceinline__ float leaky_exp(float v) {
  v = (v >= 0.f) ? v : 0.2f * v;
  return __expf(fminf(v, 80.f));
}

// ---- aggregation layer 1 (exp fused): block = node, wave = 128-ch tile ----
__global__ __launch_bounds__(256) void agg1_kernel(
    const int* __restrict__ row_off, const int* __restrict__ src_csr,
    const float* __restrict__ el, const float* __restrict__ er,
    const __half* __restrict__ fth, const float* __restrict__ bias,
    __half* __restrict__ out, const int* __restrict__ nord) {
  int t = threadIdx.x;
  int w = t >> 6, lane = t & 63;
  int n = nord[blockIdx.x];
  int e = lane >> 4;
  int sub = lane & 15;
  int chb = w * 128 + sub * 8;
  int h = chb >> 6;
  int beg = row_off[n], end = row_off[n + 1];
  float er_h = er[n * 8 + h];
  float s_run = 0.f;
  float acc[8] = {0.f, 0.f, 0.f, 0.f, 0.f, 0.f, 0.f, 0.f};
  if (beg < end) {
    int iA = min(beg + e, end - 1);
    bool okA = (beg + e) < end;
    int sA = src_csr[iA];
    int iB = min(beg + 4 + e, end - 1);
    bool okB = (beg + 4 + e) < end;
    int sB = src_csr[iB];
    float elA = el[sA * 8 + h];
    uint4 ftA = *reinterpret_cast<const uint4*>(fth + (size_t)sA * F1 + chb);
    for (int c = beg; c < end; c += 4) {
      int iC = min(c + 8 + e, end - 1);
      bool okC = (c + 8 + e) < end;
      int sC = src_csr[iC];
      float elB = el[sB * 8 + h];
      uint4 ftB = *reinterpret_cast<const uint4*>(fth + (size_t)sB * F1 + chb);
      float ex = okA ? leaky_exp(elA + er_h) : 0.f;
      float2 f0 = __half22float2(*reinterpret_cast<const __half2*>(&ftA.x));
      float2 f1 = __half22float2(*reinterpret_cast<const __half2*>(&ftA.y));
      float2 f2 = __half22float2(*reinterpret_cast<const __half2*>(&ftA.z));
      float2 f3 = __half22float2(*reinterpret_cast<const __half2*>(&ftA.w));
      acc[0] += ex * f0.x; acc[1] += ex * f0.y;
      acc[2] += ex * f1.x; acc[3] += ex * f1.y;
      acc[4] += ex * f2.x; acc[5] += ex * f2.y;
      acc[6] += ex * f3.x; acc[7] += ex * f3.y;
      s_run += ex;
      sA = sB; okA = okB; elA = elB; ftA = ftB;
      sB = sC; okB = okC;
    }
  }
#pragma unroll
  for (int i = 0; i < 8; ++i) {
    acc[i] += __shfl_xor(acc[i], 16);
    acc[i] += __shfl_xor(acc[i], 32);
  }
  s_run += __shfl_xor(s_run, 16);
  s_run += __shfl_xor(s_run, 32);
  if (e == 0) {
    float inv = (s_run > 0.f) ? (1.f / s_run) : 0.f;
    uint4 pack;
    __half2* ph = reinterpret_cast<__half2*>(&pack);
#pragma unroll
    for (int i = 0; i < 4; ++i) {
      float v0 = acc[2 * i + 0] * inv + bias[chb + 2 * i + 0];
      float v1 = acc[2 * i + 1] * inv + bias[chb + 2 * i + 1];
      v0 = (v0 > 0.f) ? v0 : (__expf(v0) - 1.f);  // ELU
      v1 = (v1 > 0.f) ? v1 : (__expf(v1) - 1.f);
      ph[i] = __floats2half2_rn(v0, v1);
    }
    *reinterpret_cast<uint4*>(out + (size_t)n * F1 + chb) = pack;
  }
}

// ---- aggregation layer 2 (H=1, exp fused): wave per node ----
template <int NPB>
__global__ __launch_bounds__(NPB * 64) void agg2_kernel(
    const int* __restrict__ row_off, const int* __restrict__ src_csr,
    const float* __restrict__ el, const float* __restrict__ er,
    const __half* __restrict__ fth, const float* __restrict__ bias,
    float* __restrict__ out, const int* __restrict__ nord) {
  int t = threadIdx.x;
  int w = t >> 6, lane = t & 63;
  int n = nord[blockIdx.x * NPB + w];
  int e = lane >> 3;
  int q = lane & 7;
  int chb = q * 8;
  int beg = row_off[n], end = row_off[n + 1];
  float er_n = er[n];
  float s_run = 0.f;
  float acc[8] = {0.f, 0.f, 0.f, 0.f, 0.f, 0.f, 0.f, 0.f};
  if (beg < end) {
    int iA = min(beg + e, end - 1);
    bool okA = (beg + e) < end;
    int sA = src_csr[iA];
    int iB = min(beg + 8 + e, end - 1);
    bool okB = (beg + 8 + e) < end;
    int sB = src_csr[iB];
    float elA = el[sA];
    uint4 ftA = *reinterpret_cast<const uint4*>(fth + (size_t)sA * F2 + chb);
    for (int c = beg; c < end; c += 8) {
      int iC = min(c + 16 + e, end - 1);
      bool okC = (c + 16 + e) < end;
      int sC = src_csr[iC];
      float elB = el[sB];
      uint4 ftB = *reinterpret_cast<const uint4*>(fth + (size_t)sB * F2 + chb);
      float ex = okA ? leaky_exp(elA + er_n) : 0.f;
      float2 f0 = __half22float2(*reinterpret_cast<const __half2*>(&ftA.x));
      float2 f1 = __half22float2(*reinterpret_cast<const __half2*>(&ftA.y));
      float2 f2 = __half22float2(*reinterpret_cast<const __half2*>(&ftA.z));
      float2 f3 = __half22float2(*reinterpret_cast<const __half2*>(&ftA.w));
      acc[0] += ex * f0.x; acc[1] += ex * f0.y;
      acc[2] += ex * f1.x; acc[3] += ex * f1.y;
      acc[4] += ex * f2.x; acc[5] += ex * f2.y;
      acc[6] += ex * f3.x; acc[7] += ex * f3.y;
      s_run += ex;
      sA = sB; okA = okB; elA = elB; ftA = ftB;
      sB = sC; okB = okC;
    }
  }
#pragma unroll
  for (int i = 0; i < 8; ++i) {
    acc[i] += __shfl_xor(acc[i], 8);
    acc[i] += __shfl_xor(acc[i], 16);
    acc[i] += __shfl_xor(acc[i], 32);
  }
  s_run += __shfl_xor(s_run, 8);
  s_run += __shfl_xor(s_run, 16);
  s_run += __shfl_xor(s_run, 32);
  if (e == 0) {
    float inv = (s_run > 0.f) ? (1.f / s_run) : 0.f;
    float o[8];
#pragma unroll
    for (int i = 0; i < 8; ++i) o[i] = acc[i] * inv + bias[chb + i];
    float* op = &out[(size_t)n * F2 + chb];
    *reinterpret_cast<float4*>(op) = make_float4(o[0], o[1], o[2], o[3]);
    *reinterpret_cast<float4*>(op + 4) = make_float4(o[4], o[5], o[6], o[7]);
  }
}

extern "C" void kernel_launch(void* const* d_in, const int* in_sizes, int n_in,
                              void* d_out, int out_size, void* d_ws, size_t ws_size,
                              hipStream_t stream) {
  const float* x   = (const float*)d_in[0];
  const int*   src = (const int*)d_in[1];
  const int*   dst = (const int*)d_in[2];
  const float* W1  = (const float*)d_in[3];
  const float* al1 = (const float*)d_in[4];
  const float* ar1 = (const float*)d_in[5];
  const float* b1  = (const float*)d_in[6];
  const float* W2  = (const float*)d_in[7];
  const float* al2 = (const float*)d_in[8];
  const float* ar2 = (const float*)d_in[9];
  const float* b2  = (const float*)d_in[10];
  float* out = (float*)d_out;

  char* ws = (char*)d_ws;
  size_t off = 0;
  auto alloc = [&](size_t bytes) -> void* {
    void* p = ws + off;
    off += (bytes + 255) & ~(size_t)255;
    return p;
  };
  size_t zbeg = off;
  int* counts = (int*)alloc((size_t)N_NODES * 4);
  size_t zend = off;
  int* nord   = (int*)alloc((size_t)N_NODES * 4);
  __half* xh   = (__half*)alloc((size_t)N_NODES * IN_SIZE * 2);
  __half* W1T  = (__half*)alloc((size_t)IN_SIZE * F1 * 2);
  __half* W2T  = (__half*)alloc((size_t)F1 * F2 * 2);
  __half* ft1h = (__half*)alloc((size_t)N_NODES * F1 * 2);
  __half* h1h  = (__half*)alloc((size_t)N_NODES * F1 * 2);
  __half* ft2h = (__half*)alloc((size_t)N_NODES * F2 * 2);
  float* el1 = (float*)alloc((size_t)N_NODES * H1 * 4);
  float* er1 = (float*)alloc((size_t)N_NODES * H1 * 4);
  float* el2 = (float*)alloc((size_t)N_NODES * 4);
  float* er2 = (float*)alloc((size_t)N_NODES * 4);
  int* row_off = (int*)alloc((size_t)(N_NODES + 1) * 4);
  int* cursor  = (int*)alloc((size_t)N_NODES * 4);
  int* src_csr = (int*)alloc((size_t)N_EDGES * 4);
  (void)ws_size; (void)in_sizes; (void)n_in; (void)out_size;

  hipMemsetAsync(ws + zbeg, 0, zend - zbeg, stream);

  dim3 b256(256);
  int prep_total = PREP_X + PREP_W1 + PREP_W2 + N_EDGES;

  // prep (x cvt + W transposes + dst histogram), scan(+degree sort)
  prep_kernel<<<(prep_total + 255) / 256, b256, 0, stream>>>(
      x, xh, W1, W1T, W2, W2T, dst, counts);
  scan_kernel<<<1, 1024, 0, stream>>>(counts, row_off, cursor, nord, N_NODES);

  // ---- layer 1: GEMM1 + scatter merged (independent work, one dispatch) ----
  gemm1_scatter_kernel<<<GEMM1_BLOCKS + SCAT_BLOCKS, b256, 0, stream>>>(
      xh, W1T, ft1h, al1, ar1, el1, er1, src, dst, cursor, src_csr);
  agg1_kernel<<<N_NODES, b256, 0, stream>>>(
      row_off, src_csr, el1, er1, ft1h, b1, h1h, nord);

  // ---- layer 2 ----
  gemm_mfma<F1 / 32><<<dim3(F2 / 64, (N_NODES + 63) / 64), b256, 0, stream>>>(
      h1h, W2T, ft2h, al2, ar2, el2, er2, N_NODES, F2, H2);
  agg2_kernel<4><<<N_NODES / 4, b256, 0, stream>>>(
      row_off, src_csr, el2, er2, ft2h, b2, out, nord);
}

// Round 13
// 146.788 us; speedup vs baseline: 1.5268x; 1.0555x over previous
//
#include <hip/hip_runtime.h>
#include <hip/hip_bf16.h>
#include <hip/hip_fp16.h>
#include <math.h>

#define N_NODES 10000
#define N_EDGES 320000
#define IN_SIZE 256
#define H1 8
#define D1 64
#define F1 512
#define H2 1
#define D2 64
#define F2 64

using f16x8 = __attribute__((ext_vector_type(8))) _Float16;
using f32x4 = __attribute__((ext_vector_type(4))) float;

// ---- fused prep: x->f16, W1^T->f16, W2^T->f16, dst histogram (4 sub-counters) ----
#define PREP_X (N_NODES * IN_SIZE / 4)
#define PREP_W1 (IN_SIZE * F1)
#define PREP_W2 (F1 * F2)
__global__ void prep_kernel(const float* __restrict__ x, __half* __restrict__ xh,
                            const float* __restrict__ W1, __half* __restrict__ W1T,
                            const float* __restrict__ W2, __half* __restrict__ W2T,
                            const int* __restrict__ dst, int* __restrict__ counts4) {
  int i = blockIdx.x * blockDim.x + threadIdx.x;
  if (i < PREP_X) {
    float4 v = reinterpret_cast<const float4*>(x)[i];
    reinterpret_cast<__half2*>(xh)[i * 2 + 0] = __floats2half2_rn(v.x, v.y);
    reinterpret_cast<__half2*>(xh)[i * 2 + 1] = __floats2half2_rn(v.z, v.w);
    return;
  }
  i -= PREP_X;
  if (i < PREP_W1) {
    int k = i / F1, n = i % F1;
    W1T[(size_t)n * IN_SIZE + k] = __float2half(W1[i]);
    return;
  }
  i -= PREP_W1;
  if (i < PREP_W2) {
    int k = i / F2, n = i % F2;
    W2T[(size_t)n * F1 + k] = __float2half(W2[i]);
    return;
  }
  i -= PREP_W2;
  if (i < N_EDGES) atomicAdd(&counts4[dst[i] * 4 + (i & 3)], 1);
}

// ---- scan: row_off + 4 sub-cursors + degree counting-sort (desc) ----
__global__ __launch_bounds__(1024) void scan_kernel(const int* __restrict__ counts4,
                                                    int* __restrict__ row_off,
                                                    int* __restrict__ cursor4,
                                                    int* __restrict__ nord, int N) {
  __shared__ int part[1024];
  __shared__ int bins[129];
  __shared__ int bcur[129];
  int tid = threadIdx.x;
  int T = blockDim.x;
  int chunk = (N + T - 1) / T;
  int beg = tid * chunk;
  int end = min(beg + chunk, N);
  int s = 0;
  for (int i = beg; i < end; ++i)
    s += counts4[i * 4] + counts4[i * 4 + 1] + counts4[i * 4 + 2] + counts4[i * 4 + 3];
  part[tid] = s;
  if (tid < 129) bins[tid] = 0;
  __syncthreads();
  for (int off = 1; off < T; off <<= 1) {
    int v = (tid >= off) ? part[tid - off] : 0;
    __syncthreads();
    part[tid] += v;
    __syncthreads();
  }
  int run = (tid > 0) ? part[tid - 1] : 0;
  for (int i = beg; i < end; ++i) {
    int c0 = counts4[i * 4], c1 = counts4[i * 4 + 1];
    int c2 = counts4[i * 4 + 2], c3 = counts4[i * 4 + 3];
    int deg = c0 + c1 + c2 + c3;
    row_off[i] = run;
    cursor4[i * 4 + 0] = run;
    cursor4[i * 4 + 1] = run + c0;
    cursor4[i * 4 + 2] = run + c0 + c1;
    cursor4[i * 4 + 3] = run + c0 + c1 + c2;
    run += deg;
    atomicAdd(&bins[min(deg, 128)], 1);
  }
  if (tid == T - 1) row_off[N] = run;
  __syncthreads();
  if (tid == 0) {
    int r = 0;
    for (int d = 128; d >= 0; --d) { bcur[d] = r; r += bins[d]; }
  }
  __syncthreads();
  for (int i = beg; i < end; ++i) {
    int deg = counts4[i * 4] + counts4[i * 4 + 1] + counts4[i * 4 + 2] + counts4[i * 4 + 3];
    nord[atomicAdd(&bcur[min(deg, 128)], 1)] = i;
  }
}

// ---- shared LDS-staged MFMA GEMM tile (64 rows x 64 cols per block) ----
// B panel (64 cols x K) staged once into LDS with XOR swizzle (u^(col&7) on
// 16B units -> only 2-way bank aliasing on ds_read_b128, which is free).
// A streams from global (coalesced). 4 waves, wave = 16 rows.
template <int KSTEPS>
__device__ __forceinline__ void gemm_tile(
    int rowBase, int colBase, const __half* __restrict__ A,
    const __half* __restrict__ BT, __half* __restrict__ Ch,
    const float* __restrict__ al, const float* __restrict__ ar,
    float* __restrict__ el, float* __restrict__ er,
    int M, int Ncols, int H, f16x8* Bs) {
  constexpr int K = KSTEPS * 32;
  constexpr int UPC = 4 * KSTEPS;  // 16B units per column
  int tid = threadIdx.x;
  for (int u = tid; u < 64 * UPC; u += 256) {
    int col = u / UPC;
    int off = u % UPC;
    f16x8 v = *reinterpret_cast<const f16x8*>(BT + (size_t)(colBase + col) * K + off * 8);
    Bs[u ^ (col & 7)] = v;
  }
  __syncthreads();
  int w = tid >> 6, lane = tid & 63;
  int r16 = lane & 15, ko = lane >> 4;
  int rb = rowBase + w * 16;
  int arow = rb + r16;
  if (arow >= M) arow = M - 1;
  const f16x8* Ap = reinterpret_cast<const f16x8*>(A + (size_t)arow * K + ko * 8);
  f32x4 acc[4] = {};
#pragma unroll
  for (int kk = 0; kk < KSTEPS; ++kk) {
    f16x8 af = Ap[kk * 4];
#pragma unroll
    for (int c = 0; c < 4; ++c) {
      int col = c * 16 + r16;
      f16x8 bf = Bs[(col * UPC + kk * 4 + ko) ^ (col & 7)];
      acc[c] = __builtin_amdgcn_mfma_f32_16x16x32_f16(af, bf, acc[c], 0, 0, 0);
    }
  }
  int h = colBase >> 6;
  float alv[4], arv[4];
#pragma unroll
  for (int c = 0; c < 4; ++c) {
    alv[c] = al[colBase + c * 16 + r16];
    arv[c] = ar[colBase + c * 16 + r16];
  }
#pragma unroll
  for (int r = 0; r < 4; ++r) {
    int row = rb + (lane >> 4) * 4 + r;
    bool ok = row < M;
    float pl = 0.f, pr = 0.f;
#pragma unroll
    for (int c = 0; c < 4; ++c) {
      float v = acc[c][r];
      if (ok) Ch[(size_t)row * Ncols + colBase + c * 16 + r16] = __float2half(v);
      pl += v * alv[c];
      pr += v * arv[c];
    }
#pragma unroll
    for (int o = 8; o > 0; o >>= 1) {
      pl += __shfl_xor(pl, o);
      pr += __shfl_xor(pr, o);
    }
    if (r16 == 0 && ok) {
      el[(size_t)row * H + h] = pl;
      er[(size_t)row * H + h] = pr;
    }
  }
}

// ---- merged dispatch: GEMM1 (LDS MFMA) blocks + CSR scatter blocks ----
#define GEMM1_RB ((N_NODES + 63) / 64)
#define GEMM1_BLOCKS (8 * GEMM1_RB)
#define SCAT_BLOCKS ((N_EDGES + 255) / 256)
__global__ __launch_bounds__(256) void gemm1_scatter_kernel(
    const __half* __restrict__ A, const __half* __restrict__ BT,
    __half* __restrict__ Ch, const float* __restrict__ al,
    const float* __restrict__ ar, float* __restrict__ el,
    float* __restrict__ er,
    const int* __restrict__ src, const int* __restrict__ dst,
    int* __restrict__ cursor4, int* __restrict__ src_csr) {
  __shared__ f16x8 Bs[256 * 8];  // 32 KB (KSTEPS=8)
  if (blockIdx.x >= GEMM1_BLOCKS) {
    int e = (blockIdx.x - GEMM1_BLOCKS) * 256 + threadIdx.x;
    if (e < N_EDGES) {
      int p = atomicAdd(&cursor4[dst[e] * 4 + (e & 3)], 1);
      src_csr[p] = src[e];
    }
    return;
  }
  gemm_tile<IN_SIZE / 32>((blockIdx.x >> 3) * 64, (blockIdx.x & 7) * 64,
                          A, BT, Ch, al, ar, el, er, N_NODES, F1, H1, Bs);
}

// ---- standalone LDS GEMM (layer 2) ----
template <int KSTEPS>
__global__ __launch_bounds__(256) void gemm_lds(
    const __half* __restrict__ A, const __half* __restrict__ BT,
    __half* __restrict__ Ch, const float* __restrict__ al,
    const float* __restrict__ ar, float* __restrict__ el,
    float* __restrict__ er, int M, int Ncols, int H) {
  __shared__ f16x8 Bs[64 * 4 * KSTEPS];
  gemm_tile<KSTEPS>(blockIdx.y * 64, blockIdx.x * 64,
                    A, BT, Ch, al, ar, el, er, M, Ncols, H, Bs);
}

__device__ __forceinline__ float leaky_exp(float v) {
  v = (v >= 0.f) ? v : 0.2f * v;
  return __expf(fminf(v, 80.f));
}

// ---- aggregation layer 1 (exp fused): block = node, wave = 128-ch tile ----
__global__ __launch_bounds__(256) void agg1_kernel(
    const int* __restrict__ row_off, const int* __restrict__ src_csr,
    const float* __restrict__ el, const float* __restrict__ er,
    const __half* __restrict__ fth, const float* __restrict__ bias,
    __half* __restrict__ out, const int* __restrict__ nord) {
  int t = threadIdx.x;
  int w = t >> 6, lane = t & 63;
  int n = nord[blockIdx.x];
  int e = lane >> 4;
  int sub = lane & 15;
  int chb = w * 128 + sub * 8;
  int h = chb >> 6;
  int beg = row_off[n], end = row_off[n + 1];
  float er_h = er[n * 8 + h];
  float s_run = 0.f;
  float acc[8] = {0.f, 0.f, 0.f, 0.f, 0.f, 0.f, 0.f, 0.f};
  if (beg < end) {
    int iA = min(beg + e, end - 1);
    bool okA = (beg + e) < end;
    int sA = src_csr[iA];
    int iB = min(beg + 4 + e, end - 1);
    bool okB = (beg + 4 + e) < end;
    int sB = src_csr[iB];
    float elA = el[sA * 8 + h];
    uint4 ftA = *reinterpret_cast<const uint4*>(fth + (size_t)sA * F1 + chb);
    for (int c = beg; c < end; c += 4) {
      int iC = min(c + 8 + e, end - 1);
      bool okC = (c + 8 + e) < end;
      int sC = src_csr[iC];
      float elB = el[sB * 8 + h];
      uint4 ftB = *reinterpret_cast<const uint4*>(fth + (size_t)sB * F1 + chb);
      float ex = okA ? leaky_exp(elA + er_h) : 0.f;
      float2 f0 = __half22float2(*reinterpret_cast<const __half2*>(&ftA.x));
      float2 f1 = __half22float2(*reinterpret_cast<const __half2*>(&ftA.y));
      float2 f2 = __half22float2(*reinterpret_cast<const __half2*>(&ftA.z));
      float2 f3 = __half22float2(*reinterpret_cast<const __half2*>(&ftA.w));
      acc[0] += ex * f0.x; acc[1] += ex * f0.y;
      acc[2] += ex * f1.x; acc[3] += ex * f1.y;
      acc[4] += ex * f2.x; acc[5] += ex * f2.y;
      acc[6] += ex * f3.x; acc[7] += ex * f3.y;
      s_run += ex;
      sA = sB; okA = okB; elA = elB; ftA = ftB;
      sB = sC; okB = okC;
    }
  }
#pragma unroll
  for (int i = 0; i < 8; ++i) {
    acc[i] += __shfl_xor(acc[i], 16);
    acc[i] += __shfl_xor(acc[i], 32);
  }
  s_run += __shfl_xor(s_run, 16);
  s_run += __shfl_xor(s_run, 32);
  if (e == 0) {
    float inv = (s_run > 0.f) ? (1.f / s_run) : 0.f;
    uint4 pack;
    __half2* ph = reinterpret_cast<__half2*>(&pack);
#pragma unroll
    for (int i = 0; i < 4; ++i) {
      float v0 = acc[2 * i + 0] * inv + bias[chb + 2 * i + 0];
      float v1 = acc[2 * i + 1] * inv + bias[chb + 2 * i + 1];
      v0 = (v0 > 0.f) ? v0 : (__expf(v0) - 1.f);  // ELU
      v1 = (v1 > 0.f) ? v1 : (__expf(v1) - 1.f);
      ph[i] = __floats2half2_rn(v0, v1);
    }
    *reinterpret_cast<uint4*>(out + (size_t)n * F1 + chb) = pack;
  }
}

// ---- aggregation layer 2 (H=1, exp fused): wave per node ----
template <int NPB>
__global__ __launch_bounds__(NPB * 64) void agg2_kernel(
    const int* __restrict__ row_off, const int* __restrict__ src_csr,
    const float* __restrict__ el, const float* __restrict__ er,
    const __half* __restrict__ fth, const float* __restrict__ bias,
    float* __restrict__ out, const int* __restrict__ nord) {
  int t = threadIdx.x;
  int w = t >> 6, lane = t & 63;
  int n = nord[blockIdx.x * NPB + w];
  int e = lane >> 3;
  int q = lane & 7;
  int chb = q * 8;
  int beg = row_off[n], end = row_off[n + 1];
  float er_n = er[n];
  float s_run = 0.f;
  float acc[8] = {0.f, 0.f, 0.f, 0.f, 0.f, 0.f, 0.f, 0.f};
  if (beg < end) {
    int iA = min(beg + e, end - 1);
    bool okA = (beg + e) < end;
    int sA = src_csr[iA];
    int iB = min(beg + 8 + e, end - 1);
    bool okB = (beg + 8 + e) < end;
    int sB = src_csr[iB];
    float elA = el[sA];
    uint4 ftA = *reinterpret_cast<const uint4*>(fth + (size_t)sA * F2 + chb);
    for (int c = beg; c < end; c += 8) {
      int iC = min(c + 16 + e, end - 1);
      bool okC = (c + 16 + e) < end;
      int sC = src_csr[iC];
      float elB = el[sB];
      uint4 ftB = *reinterpret_cast<const uint4*>(fth + (size_t)sB * F2 + chb);
      float ex = okA ? leaky_exp(elA + er_n) : 0.f;
      float2 f0 = __half22float2(*reinterpret_cast<const __half2*>(&ftA.x));
      float2 f1 = __half22float2(*reinterpret_cast<const __half2*>(&ftA.y));
      float2 f2 = __half22float2(*reinterpret_cast<const __half2*>(&ftA.z));
      float2 f3 = __half22float2(*reinterpret_cast<const __half2*>(&ftA.w));
      acc[0] += ex * f0.x; acc[1] += ex * f0.y;
      acc[2] += ex * f1.x; acc[3] += ex * f1.y;
      acc[4] += ex * f2.x; acc[5] += ex * f2.y;
      acc[6] += ex * f3.x; acc[7] += ex * f3.y;
      s_run += ex;
      sA = sB; okA = okB; elA = elB; ftA = ftB;
      sB = sC; okB = okC;
    }
  }
#pragma unroll
  for (int i = 0; i < 8; ++i) {
    acc[i] += __shfl_xor(acc[i], 8);
    acc[i] += __shfl_xor(acc[i], 16);
    acc[i] += __shfl_xor(acc[i], 32);
  }
  s_run += __shfl_xor(s_run, 8);
  s_run += __shfl_xor(s_run, 16);
  s_run += __shfl_xor(s_run, 32);
  if (e == 0) {
    float inv = (s_run > 0.f) ? (1.f / s_run) : 0.f;
    float o[8];
#pragma unroll
    for (int i = 0; i < 8; ++i) o[i] = acc[i] * inv + bias[chb + i];
    float* op = &out[(size_t)n * F2 + chb];
    *reinterpret_cast<float4*>(op) = make_float4(o[0], o[1], o[2], o[3]);
    *reinterpret_cast<float4*>(op + 4) = make_float4(o[4], o[5], o[6], o[7]);
  }
}

extern "C" void kernel_launch(void* const* d_in, const int* in_sizes, int n_in,
                              void* d_out, int out_size, void* d_ws, size_t ws_size,
                              hipStream_t stream) {
  const float* x   = (const float*)d_in[0];
  const int*   src = (const int*)d_in[1];
  const int*   dst = (const int*)d_in[2];
  const float* W1  = (const float*)d_in[3];
  const float* al1 = (const float*)d_in[4];
  const float* ar1 = (const float*)d_in[5];
  const float* b1  = (const float*)d_in[6];
  const float* W2  = (const float*)d_in[7];
  const float* al2 = (const float*)d_in[8];
  const float* ar2 = (const float*)d_in[9];
  const float* b2  = (const float*)d_in[10];
  float* out = (float*)d_out;

  char* ws = (char*)d_ws;
  size_t off = 0;
  auto alloc = [&](size_t bytes) -> void* {
    void* p = ws + off;
    off += (bytes + 255) & ~(size_t)255;
    return p;
  };
  size_t zbeg = off;
  int* counts4 = (int*)alloc((size_t)N_NODES * 4 * 4);
  size_t zend = off;
  int* cursor4 = (int*)alloc((size_t)N_NODES * 4 * 4);
  int* nord    = (int*)alloc((size_t)N_NODES * 4);
  __half* xh   = (__half*)alloc((size_t)N_NODES * IN_SIZE * 2);
  __half* W1T  = (__half*)alloc((size_t)IN_SIZE * F1 * 2);
  __half* W2T  = (__half*)alloc((size_t)F1 * F2 * 2);
  __half* ft1h = (__half*)alloc((size_t)N_NODES * F1 * 2);
  __half* h1h  = (__half*)alloc((size_t)N_NODES * F1 * 2);
  __half* ft2h = (__half*)alloc((size_t)N_NODES * F2 * 2);
  float* el1 = (float*)alloc((size_t)N_NODES * H1 * 4);
  float* er1 = (float*)alloc((size_t)N_NODES * H1 * 4);
  float* el2 = (float*)alloc((size_t)N_NODES * 4);
  float* er2 = (float*)alloc((size_t)N_NODES * 4);
  int* row_off = (int*)alloc((size_t)(N_NODES + 1) * 4);
  int* src_csr = (int*)alloc((size_t)N_EDGES * 4);
  (void)ws_size; (void)in_sizes; (void)n_in; (void)out_size;

  hipMemsetAsync(ws + zbeg, 0, zend - zbeg, stream);

  dim3 b256(256);
  int prep_total = PREP_X + PREP_W1 + PREP_W2 + N_EDGES;

  // prep (x cvt + W transposes + dst histogram), scan(+sub-cursors, sort)
  prep_kernel<<<(prep_total + 255) / 256, b256, 0, stream>>>(
      x, xh, W1, W1T, W2, W2T, dst, counts4);
  scan_kernel<<<1, 1024, 0, stream>>>(counts4, row_off, cursor4, nord, N_NODES);

  // ---- layer 1: GEMM1 + scatter merged ----
  gemm1_scatter_kernel<<<GEMM1_BLOCKS + SCAT_BLOCKS, b256, 0, stream>>>(
      xh, W1T, ft1h, al1, ar1, el1, er1, src, dst, cursor4, src_csr);
  agg1_kernel<<<N_NODES, b256, 0, stream>>>(
      row_off, src_csr, el1, er1, ft1h, b1, h1h, nord);

  // ---- layer 2 ----
  gemm_lds<F1 / 32><<<dim3(F2 / 64, (N_NODES + 63) / 64), b256, 0, stream>>>(
      h1h, W2T, ft2h, al2, ar2, el2, er2, N_NODES, F2, H2);
  agg2_kernel<4><<<N_NODES / 4, b256, 0, stream>>>(
      row_off, src_csr, el2, er2, ft2h, b2, out, nord);
}